// Round 1
// 66.810 us; speedup vs baseline: 1.0157x; 1.0157x over previous
//
#include <hip/hip_runtime.h>

// W_MUL = sqrt(2)/sqrt(5)
#define WMUL 0.63245553203367586640f

typedef float v2f __attribute__((ext_vector_type(2)));   // (re, im)
typedef float v4f __attribute__((ext_vector_type(4)));   // two cplx

__device__ __forceinline__ v4f cat(v2f a, v2f b) { return __builtin_shufflevector(a, b, 0, 1, 2, 3); }
__device__ __forceinline__ v2f lo2(v4f t) { return __builtin_shufflevector(t, t, 0, 1); }
__device__ __forceinline__ v2f hi2(v4f t) { return __builtin_shufflevector(t, t, 2, 3); }

// ---- cold-path C complex math ----
__device__ __forceinline__ v2f cmul_c(v2f a, v2f b) {
    v2f r = { a.x*b.x - a.y*b.y, a.x*b.y + a.y*b.x };
    return r;
}
__device__ __forceinline__ v2f cmacc_c(v2f acc, v2f a, v2f b) {
    acc.x += a.x*b.x - a.y*b.y;
    acc.y += a.x*b.y + a.y*b.x;
    return acc;
}

// ---- hot-path packed complex MACs (2 instrs instead of 4) ----
// d += a*b:  lo += a.re*b.re - a.im*b.im ; hi += a.re*b.im + a.im*b.re
__device__ __forceinline__ void cmacc_pk(v2f& d, v2f a, v2f b) {
    asm("v_pk_fma_f32 %0, %1, %2, %0 op_sel_hi:[0,1,1]\n\t"
        "v_pk_fma_f32 %0, %1, %2, %0 op_sel:[1,1,0] op_sel_hi:[1,0,1] neg_lo:[1,0,0]"
        : "+v"(d) : "v"(a), "v"(b));
}
// d += conj(a)*b: lo += a.re*b.re + a.im*b.im ; hi += a.re*b.im - a.im*b.re
__device__ __forceinline__ void cmacc_cj_pk(v2f& d, v2f a, v2f b) {
    asm("v_pk_fma_f32 %0, %1, %2, %0 op_sel_hi:[0,1,1]\n\t"
        "v_pk_fma_f32 %0, %1, %2, %0 op_sel:[1,1,0] op_sel_hi:[1,0,1] neg_hi:[1,0,0]"
        : "+v"(d) : "v"(a), "v"(b));
}
// d += conj(a)*m, m real duplicated in both halves: lo += a.re*m ; hi += -a.im*m
__device__ __forceinline__ void cmacc_rj_pk(v2f& d, v2f a, v2f m) {
    asm("v_pk_fma_f32 %0, %1, %2, %0 neg_hi:[1,0,0]"
        : "+v"(d) : "v"(a), "v"(m));
}

// 256 threads, per-thread 2x2 tile (rows {2i0,2i0+1}, cols {2j0,2j0+1}).
// LDS arena (v2f units, 58.9 KB):
//   CLA  [0   ..1023]  [k*32+j] = conj(LA[j][k])
//   CLB  [1024..2047]
//   CL2A [2048..3071]
//   TAT  [3072..4159]  [j*34+i] = TA[i][j]   (pad 34)
//   TBT  [4160..5247]
//   A1p  [5248..6303]  [r*33+c]              (pad 33; head aliases gates[80])
//   B1p  [6304..7359]
//   Sarr aliases [3072..3079] (TAT dead after P4)
//   Np   aliases [0..1087]    (CLA/CLB dead after P4)
//   TFT  aliases [3072..4159] (Sarr dead after P5b)
//   MAs  aliases v2f [5328..5839] as float[1024]  (after gates; dead after P3;
//   MBs  aliases v2f [5840..6351] as float[1024]   A1p/B1p first written in P4)
__global__ __launch_bounds__(256)
void qmutual_kernel(const float* __restrict__ A, const float* __restrict__ B,
                    const float* __restrict__ weight, float* __restrict__ out,
                    int out_size)
{
    __shared__ __align__(16) v2f arena[7360];
    v2f* CLA   = arena;
    v2f* CLB   = arena + 1024;
    v2f* CL2A  = arena + 2048;
    v2f* TAT   = arena + 3072;
    v2f* TBT   = arena + 4160;
    v2f* A1p   = arena + 5248;
    v2f* B1p   = arena + 6304;
    v2f* Sarr  = arena + 3072;
    v2f* Np    = arena;
    v2f* TFT   = arena + 3072;
    v2f* gates = arena + 5248;   // [layer*10+q][2][2], 80 cplx, dead after P2
    float* MAs = (float*)(arena + 5328);  // 1024 fp32, staged MA; dead after P3
    float* MBs = (float*)(arena + 5840);  // 1024 fp32, staged MB; dead after P3

    const int tid = threadIdx.x;
    const int i0 = tid >> 4, j0 = tid & 15;
    const int r0 = 2*i0, c0 = 2*j0;
    const int blk = blockIdx.x;
    const float* MA = blk ? B : A;   // block 0: A(x)B path, block 1: B(x)A path
    const float* MB = blk ? A : B;

    // ---- P0: issue the (L2-cold) input loads FIRST; they retire into LDS
    // just before P3's barrier, so the ~900-cycle HBM miss overlaps P1+P2.
    const float4 va = *(const float4*)&MA[tid*4];
    const float4 vb = *(const float4*)&MB[tid*4];

    // ---- P1: combined per-qubit gates G = Rz*Ry*Rx ----
    if (tid < 20) {
        const int layer = tid / 10, q = tid % 10;
        const float w0 = weight[6*q + 3*layer + 0] * WMUL;
        const float w1 = weight[6*q + 3*layer + 1] * WMUL;
        const float w2 = weight[6*q + 3*layer + 2] * WMUL;
        float cx, sx, cy, sy, cz, sz;
        __sincosf(0.5f*w0, &sx, &cx);
        __sincosf(0.5f*w1, &sy, &cy);
        __sincosf(0.5f*w2, &sz, &cz);
        v2f rx[2][2] = { { {cx,0.f}, {0.f,-sx} }, { {0.f,-sx}, {cx,0.f} } };
        v2f ry[2][2] = { { {cy,0.f}, {-sy,0.f} }, { {sy,0.f}, {cy,0.f} } };
        const v2f rz0 = {cz, -sz}, rz1 = {cz, sz};
        v2f m[2][2];
        #pragma unroll
        for (int r = 0; r < 2; ++r)
            #pragma unroll
            for (int c = 0; c < 2; ++c)
                m[r][c] = cmacc_c(cmul_c(ry[r][0], rx[0][c]), ry[r][1], rx[1][c]);
        v2f* g = gates + tid*4;
        g[0] = cmul_c(rz0, m[0][0]); g[1] = cmul_c(rz0, m[0][1]);
        g[2] = cmul_c(rz1, m[1][0]); g[3] = cmul_c(rz1, m[1][1]);
    }
    __syncthreads();

    // ---- P2: build conj-Kronecker matrices, 4 entries/thread each ----
    {
        v2f vals[3][2][2];
        #pragma unroll
        for (int mat = 0; mat < 3; ++mat) {
            const int gbase = (mat == 0) ? 0 : (mat == 1 ? 5 : 10);
            #pragma unroll
            for (int kk = 0; kk < 2; ++kk)
                #pragma unroll
                for (int jj = 0; jj < 2; ++jj) {
                    const int k = r0 + kk, j = c0 + jj;
                    v2f v = {1.f, 0.f};
                    #pragma unroll
                    for (int q = 0; q < 5; ++q) {
                        const int rb = (j >> (4-q)) & 1;
                        const int cb = (k >> (4-q)) & 1;
                        v = cmul_c(v, gates[(gbase+q)*4 + rb*2 + cb]);
                    }
                    v2f cv = { v.x, -v.y };
                    vals[mat][kk][jj] = cv;
                }
        }
        #pragma unroll
        for (int kk = 0; kk < 2; ++kk) {
            *(v4f*)&CLA [(r0+kk)*32 + c0] = cat(vals[0][kk][0], vals[0][kk][1]);
            *(v4f*)&CLB [(r0+kk)*32 + c0] = cat(vals[1][kk][0], vals[1][kk][1]);
            *(v4f*)&CL2A[(r0+kk)*32 + c0] = cat(vals[2][kk][0], vals[2][kk][1]);
        }
        // park the staged inputs in LDS (region is past gates[80]; A1p/B1p
        // are first written in P4, after MAs/MBs are dead)
        *(float4*)&MAs[tid*4] = va;
        *(float4*)&MBs[tid*4] = vb;
    }
    __syncthreads();

    // ---- P3: TA = LA @ MA, TB = LB @ MB (MA,MB real; conj(CLA)=LA) ----
    {
        v2f ta[2][2] = {}, tb[2][2] = {};
        #pragma unroll
        for (int k = 0; k < 32; ++k) {
            const v4f xa = *(const v4f*)&CLA[k*32 + r0];
            const v4f xb = *(const v4f*)&CLB[k*32 + r0];
            const float2 ma = *(const float2*)&MAs[k*32 + c0];
            const float2 mb = *(const float2*)&MBs[k*32 + c0];
            const v2f xa0 = lo2(xa), xa1 = hi2(xa);
            const v2f xb0 = lo2(xb), xb1 = hi2(xb);
            const v2f mx = {ma.x, ma.x}, my = {ma.y, ma.y};
            const v2f nx = {mb.x, mb.x}, ny = {mb.y, mb.y};
            cmacc_rj_pk(ta[0][0], xa0, mx); cmacc_rj_pk(ta[0][1], xa0, my);
            cmacc_rj_pk(ta[1][0], xa1, mx); cmacc_rj_pk(ta[1][1], xa1, my);
            cmacc_rj_pk(tb[0][0], xb0, nx); cmacc_rj_pk(tb[0][1], xb0, ny);
            cmacc_rj_pk(tb[1][0], xb1, nx); cmacc_rj_pk(tb[1][1], xb1, ny);
        }
        #pragma unroll
        for (int g = 0; g < 2; ++g) {
            *(v4f*)&TAT[(c0+g)*34 + r0] = cat(ta[0][g], ta[1][g]);
            *(v4f*)&TBT[(c0+g)*34 + r0] = cat(tb[0][g], tb[1][g]);
        }
    }
    __syncthreads();

    // ---- P4: A1 = TA @ LA^H, B1 = TB @ LB^H (conj(LA[c][k]) = CLA[k*32+c]) ----
    {
        v2f a1[2][2] = {}, b1[2][2] = {};
        #pragma unroll
        for (int k = 0; k < 32; ++k) {
            const v4f t  = *(const v4f*)&TAT[k*34 + r0];
            const v4f u  = *(const v4f*)&TBT[k*34 + r0];
            const v4f ca = *(const v4f*)&CLA[k*32 + c0];
            const v4f cb = *(const v4f*)&CLB[k*32 + c0];
            const v2f t0 = lo2(t), t1 = hi2(t), u0 = lo2(u), u1 = hi2(u);
            const v2f ca0 = lo2(ca), ca1 = hi2(ca), cb0 = lo2(cb), cb1 = hi2(cb);
            cmacc_pk(a1[0][0], t0, ca0); cmacc_pk(a1[0][1], t0, ca1);
            cmacc_pk(a1[1][0], t1, ca0); cmacc_pk(a1[1][1], t1, ca1);
            cmacc_pk(b1[0][0], u0, cb0); cmacc_pk(b1[0][1], u0, cb1);
            cmacc_pk(b1[1][0], u1, cb0); cmacc_pk(b1[1][1], u1, cb1);
        }
        #pragma unroll
        for (int p = 0; p < 2; ++p)
            #pragma unroll
            for (int g = 0; g < 2; ++g) {
                A1p[(r0+p)*33 + c0+g] = a1[p][g];
                B1p[(r0+p)*33 + c0+g] = b1[p][g];
            }
    }
    __syncthreads();

    // ---- P5a: 8 B-trace sums S[p][eps][del] = sum_{kb%2==p} B1[(eps<<4)^G(kb)][(del<<4)^G(kb)]
    // wave-parallel: 128 threads, one term each, 16-lane shuffle tree
    if (tid < 128) {
        const int s = tid >> 4, m = tid & 15;
        const int p = (s >> 2) & 1, eps = (s >> 1) & 1, del = s & 1;
        const int kb = 2*m + p;
        const int g  = kb ^ (kb >> 1);
        v2f v = B1p[((eps<<4)^g)*33 + ((del<<4)^g)];
        #pragma unroll
        for (int off = 8; off; off >>= 1) {
            v.x += __shfl_xor(v.x, off, 16);
            v.y += __shfl_xor(v.y, off, 16);
        }
        if (m == 0) Sarr[s] = v;   // TAT region dead after P4
    }
    __syncthreads();

    // ---- P5b: N[r,c] = A1[G(r)][G(c)]*S[0][r&1][c&1] + A1[G(r)^24][G(c)^24]*S[1][r&1][c&1]
    {
        const int gr0 = r0 ^ (r0 >> 1), gr1 = (r0+1) ^ ((r0+1) >> 1);
        const int gc0 = c0 ^ (c0 >> 1), gc1 = (c0+1) ^ ((c0+1) >> 1);
        const v2f A00 = A1p[gr0*33 + gc0],        A01 = A1p[gr0*33 + gc1];
        const v2f A10 = A1p[gr1*33 + gc0],        A11 = A1p[gr1*33 + gc1];
        const v2f X00 = A1p[(gr0^24)*33 + (gc0^24)], X01 = A1p[(gr0^24)*33 + (gc1^24)];
        const v2f X10 = A1p[(gr1^24)*33 + (gc0^24)], X11 = A1p[(gr1^24)*33 + (gc1^24)];
        v2f n[2][2] = {};
        cmacc_pk(n[0][0], A00, Sarr[0]); cmacc_pk(n[0][0], X00, Sarr[4]);
        cmacc_pk(n[0][1], A01, Sarr[1]); cmacc_pk(n[0][1], X01, Sarr[5]);
        cmacc_pk(n[1][0], A10, Sarr[2]); cmacc_pk(n[1][0], X10, Sarr[6]);
        cmacc_pk(n[1][1], A11, Sarr[3]); cmacc_pk(n[1][1], X11, Sarr[7]);
        #pragma unroll
        for (int p = 0; p < 2; ++p)
            *(v4f*)&Np[(r0+p)*34 + c0] = cat(n[p][0], n[p][1]);   // CLA/CLB dead
    }
    __syncthreads();

    // ---- P6: TF = L2A @ N  (L2A[i][k] = conj(CL2A[k*32+i])) ----
    {
        v2f tf[2][2] = {};
        #pragma unroll
        for (int k = 0; k < 32; ++k) {
            const v4f x = *(const v4f*)&CL2A[k*32 + r0];
            const v4f m = *(const v4f*)&Np[k*34 + c0];
            const v2f x0 = lo2(x), x1 = hi2(x), m0 = lo2(m), m1 = hi2(m);
            cmacc_cj_pk(tf[0][0], x0, m0); cmacc_cj_pk(tf[0][1], x0, m1);
            cmacc_cj_pk(tf[1][0], x1, m0); cmacc_cj_pk(tf[1][1], x1, m1);
        }
        #pragma unroll
        for (int g = 0; g < 2; ++g)
            *(v4f*)&TFT[(c0+g)*34 + r0] = cat(tf[0][g], tf[1][g]);  // Sarr dead
    }
    __syncthreads();

    // ---- P7: R = TF @ L2A^H, store ----
    {
        v2f rr[2][2] = {};
        #pragma unroll
        for (int k = 0; k < 32; ++k) {
            const v4f t  = *(const v4f*)&TFT[k*34 + r0];
            const v4f c2 = *(const v4f*)&CL2A[k*32 + c0];
            const v2f t0 = lo2(t), t1 = hi2(t), c20 = lo2(c2), c21 = hi2(c2);
            cmacc_pk(rr[0][0], t0, c20); cmacc_pk(rr[0][1], t0, c21);
            cmacc_pk(rr[1][0], t1, c20); cmacc_pk(rr[1][1], t1, c21);
        }
        if (out_size >= 4096) {
            #pragma unroll
            for (int p = 0; p < 2; ++p)
                *(v4f*)&out[blk*2048 + (r0+p)*64 + 4*j0] = cat(rr[p][0], rr[p][1]);
        } else {
            #pragma unroll
            for (int p = 0; p < 2; ++p) {
                float2 v = { rr[p][0].x, rr[p][1].x };
                *(float2*)&out[blk*1024 + (r0+p)*32 + c0] = v;
            }
        }
    }
}

extern "C" void kernel_launch(void* const* d_in, const int* in_sizes, int n_in,
                              void* d_out, int out_size, void* d_ws, size_t ws_size,
                              hipStream_t stream) {
    const float* A = (const float*)d_in[0];   // inputA 32x32 fp32
    const float* B = (const float*)d_in[1];   // inputB 32x32 fp32
    const float* w = (const float*)d_in[2];   // weight 60 fp32
    float* out = (float*)d_out;
    qmutual_kernel<<<2, 256, 0, stream>>>(A, B, w, out, out_size);
}